// Round 7
// baseline (248.286 us; speedup 1.0000x reference)
//
#include <hip/hip_runtime.h>

// VectorQuantizer: x [32,64,64,64] f32, emb [512,64] f32 -> out [32,64,64,64] f32
// out[b,:,h,w] = emb[argmin_k dists], reproducing numpy FLOAT32 bit semantics
// (verified absmax==0 in R2-R6):
//   dists[k] = fl( fl(x_sq + e_sq[k]) - fl(2*dot[k]) )
//   dot      = sequential-c FMA chain; x_sq/e_sq = numpy pairwise-8 sums;
//   argmin: ascending k, strict <.
//
// R7: P=2 pixel reuse. R2-R6 all plateau at ~190us with ~1.25 aux-VALU per
// FMA + 33% stall; the invariant is e-delivery at 1 dword/FMA (SGPR working
// set 1024 dwords/tile >> ~100 free SGPRs -> chunked s_load waits / partial
// VMEM demotion). Each thread now scores 2 pixels, so every emb scalar feeds
// 2 FMAs: e-dwords per FMA halve, aux+stall should halve with it.
//   block = 512 thr / 8 waves, k-split 8 (64 codes/wave), 128-pixel LDS tile
//   (stride 68 -> 0 conflicts, measured R6), d0[16]+d1[16] accumulators.
//   Reduction arrays overlay the dead x-tile -> LDS 34816 B -> 4 blocks/CU.

#define KNUM 512
#define CDIM 64
#define BPIX 128              // pixels per block
#define NW   8                // waves per block (= k-split)
#define KPW  (KNUM / NW)      // 64 codes per wave
#define TK   16               // rows per k-tile
#define XPAD 68               // x-tile row stride (0-conflict b128 pattern)

__global__ __launch_bounds__(256) void vq_prep(const float* __restrict__ emb,
                                               float* __restrict__ e_sq)
{
    const int k = blockIdx.x * 256 + threadIdx.x;
    if (k < KNUM) {
        const float* e = emb + k * CDIM;
        float r[8];
        #pragma unroll
        for (int j = 0; j < 8; ++j) r[j] = __fmul_rn(e[j], e[j]);
        #pragma unroll
        for (int i = 8; i < CDIM; i += 8)
            #pragma unroll
            for (int j = 0; j < 8; ++j)
                r[j] = __fadd_rn(r[j], __fmul_rn(e[i + j], e[i + j]));
        e_sq[k] = __fadd_rn(
            __fadd_rn(__fadd_rn(r[0], r[1]), __fadd_rn(r[2], r[3])),
            __fadd_rn(__fadd_rn(r[4], r[5]), __fadd_rn(r[6], r[7])));
    }
}

__device__ __forceinline__ float xsq_pairwise8(const float* xr)
{
    float r[8];
    {
        const float4 a = *(const float4*)&xr[0];
        const float4 c = *(const float4*)&xr[4];
        r[0] = __fmul_rn(a.x, a.x); r[1] = __fmul_rn(a.y, a.y);
        r[2] = __fmul_rn(a.z, a.z); r[3] = __fmul_rn(a.w, a.w);
        r[4] = __fmul_rn(c.x, c.x); r[5] = __fmul_rn(c.y, c.y);
        r[6] = __fmul_rn(c.z, c.z); r[7] = __fmul_rn(c.w, c.w);
    }
    #pragma unroll
    for (int i = 1; i < 8; ++i) {
        const float4 a = *(const float4*)&xr[8 * i];
        const float4 c = *(const float4*)&xr[8 * i + 4];
        r[0] = __fadd_rn(r[0], __fmul_rn(a.x, a.x));
        r[1] = __fadd_rn(r[1], __fmul_rn(a.y, a.y));
        r[2] = __fadd_rn(r[2], __fmul_rn(a.z, a.z));
        r[3] = __fadd_rn(r[3], __fmul_rn(a.w, a.w));
        r[4] = __fadd_rn(r[4], __fmul_rn(c.x, c.x));
        r[5] = __fadd_rn(r[5], __fmul_rn(c.y, c.y));
        r[6] = __fadd_rn(r[6], __fmul_rn(c.z, c.z));
        r[7] = __fadd_rn(r[7], __fmul_rn(c.w, c.w));
    }
    return __fadd_rn(
        __fadd_rn(__fadd_rn(r[0], r[1]), __fadd_rn(r[2], r[3])),
        __fadd_rn(__fadd_rn(r[4], r[5]), __fadd_rn(r[6], r[7])));
}

__global__ __launch_bounds__(512) void vq_main(const float* __restrict__ x,
                                               const float* __restrict__ emb,
                                               const float* __restrict__ e_sq,
                                               float* __restrict__ out)
{
    __shared__ float xt[BPIX][XPAD];   // 34816 B; overlaid by reduction later

    const int tid  = threadIdx.x;
    const int pix0 = blockIdx.x * BPIX;
    const int b    = pix0 >> 12;            // H*W = 4096 (128 | 4096: no cross)
    const int hw0  = pix0 & 4095;
    const float* xb = x + (((size_t)b * CDIM) << 12) + hw0;

    // ---- stage x tile: thread (g = tid>>7, p = tid&127), 4 b128 chunks ----
    {
        const int p = tid & 127;
        const int g = tid >> 7;              // 0..3
        #pragma unroll
        for (int i = 0; i < 4; ++i) {
            const int c0 = 4 * (g + 4 * i);  // 4g, 4g+16, 4g+32, 4g+48
            float4 v;
            v.x = xb[((size_t)(c0 + 0) << 12) + p];   // 512 B coalesced each
            v.y = xb[((size_t)(c0 + 1) << 12) + p];
            v.z = xb[((size_t)(c0 + 2) << 12) + p];
            v.w = xb[((size_t)(c0 + 3) << 12) + p];
            *(float4*)&xt[p][c0] = v;        // ds_write_b128, 0-conflict layout
        }
    }
    __syncthreads();

    const int l = tid & 63;                                   // lane
    const int q = __builtin_amdgcn_readfirstlane(tid >> 6);   // wave id 0..7 (UNIFORM)

    // x_sq for this lane's two pixels (numpy pairwise-8, verified bit-exact)
    const float xs0 = xsq_pairwise8(xt[l]);
    const float xs1 = xsq_pairwise8(xt[l + 64]);

    // scan this octant's 64 codes, 16 rows/tile, 2 pixels share each e scalar
    const int k0 = q * KPW;                  // uniform
    float best0 = 3.4e38f, best1 = 3.4e38f;
    int bi0 = k0, bi1 = k0;
    #pragma unroll 1
    for (int kt = 0; kt < KPW; kt += TK) {
        const int k = k0 + kt;               // uniform
        const float* e = emb + (size_t)k * CDIM;   // scalar addr -> s_load
        float d0[TK], d1[TK];
        #pragma unroll
        for (int r = 0; r < TK; ++r) { d0[r] = 0.f; d1[r] = 0.f; }
        #pragma unroll
        for (int c4 = 0; c4 < 16; ++c4) {
            const float4 xv0 = *(const float4*)&xt[l     ][4 * c4]; // ds_read_b128
            const float4 xv1 = *(const float4*)&xt[l + 64][4 * c4];
            #pragma unroll
            for (int j = 0; j < 4; ++j) {    // c = 4*c4+j ascending per row
                const float xc0 = (j == 0) ? xv0.x : (j == 1) ? xv0.y
                                : (j == 2) ? xv0.z : xv0.w;
                const float xc1 = (j == 0) ? xv1.x : (j == 1) ? xv1.y
                                : (j == 2) ? xv1.z : xv1.w;
                #pragma unroll
                for (int r = 0; r < TK; ++r) {
                    const float ev = e[r * CDIM + 4 * c4 + j];  // shared scalar
                    d0[r] = fmaf(xc0, ev, d0[r]);
                    d1[r] = fmaf(xc1, ev, d1[r]);
                }
            }
        }
        #pragma unroll
        for (int r = 0; r < TK; ++r) {       // ascending r, strict <
            const float eq = e_sq[k + r];    // uniform -> s_load
            const float s0 = __fsub_rn(__fadd_rn(xs0, eq), __fmul_rn(2.0f, d0[r]));
            const float s1 = __fsub_rn(__fadd_rn(xs1, eq), __fmul_rn(2.0f, d1[r]));
            if (s0 < best0) { best0 = s0; bi0 = k + r; }
            if (s1 < best1) { best1 = s1; bi1 = k + r; }
        }
    }

    __syncthreads();                         // x-tile dead; overlay reduction
    float* rb = &xt[0][0];                   // [NW][BPIX] floats (4 KB)
    int*   ri = (int*)(&xt[0][0]) + NW * BPIX;   // next 4 KB
    rb[q * BPIX + l     ] = best0;  ri[q * BPIX + l     ] = bi0;
    rb[q * BPIX + l + 64] = best1;  ri[q * BPIX + l + 64] = bi1;
    __syncthreads();

    // combine octants ascending (strict < => global first-occurrence argmin),
    // then thread (g2, p2) writes 16 channels of pixel p2
    const int p2 = tid & 127;
    const int g2 = tid >> 7;                 // 0..3
    float wb = rb[p2];
    int   wi = ri[p2];
    #pragma unroll
    for (int qq = 1; qq < NW; ++qq) {
        const float bq = rb[qq * BPIX + p2];
        const int   iq = ri[qq * BPIX + p2];
        if (bq < wb) { wb = bq; wi = iq; }
    }

    const float* er = emb + ((size_t)wi * CDIM) + g2 * 16;
    const float4 v0 = *(const float4*)(er);
    const float4 v1 = *(const float4*)(er + 4);
    const float4 v2 = *(const float4*)(er + 8);
    const float4 v3 = *(const float4*)(er + 12);
    float* ob = out + (((size_t)b * CDIM) << 12) + (((size_t)(g2 * 16)) << 12) + hw0 + p2;
    ob[(size_t) 0 << 12] = v0.x;  ob[(size_t) 1 << 12] = v0.y;
    ob[(size_t) 2 << 12] = v0.z;  ob[(size_t) 3 << 12] = v0.w;
    ob[(size_t) 4 << 12] = v1.x;  ob[(size_t) 5 << 12] = v1.y;
    ob[(size_t) 6 << 12] = v1.z;  ob[(size_t) 7 << 12] = v1.w;
    ob[(size_t) 8 << 12] = v2.x;  ob[(size_t) 9 << 12] = v2.y;
    ob[(size_t)10 << 12] = v2.z;  ob[(size_t)11 << 12] = v2.w;
    ob[(size_t)12 << 12] = v3.x;  ob[(size_t)13 << 12] = v3.y;
    ob[(size_t)14 << 12] = v3.z;  ob[(size_t)15 << 12] = v3.w;
}

extern "C" void kernel_launch(void* const* d_in, const int* in_sizes, int n_in,
                              void* d_out, int out_size, void* d_ws, size_t ws_size,
                              hipStream_t stream)
{
    const float* x   = (const float*)d_in[0];
    const float* emb = (const float*)d_in[1];
    float* out  = (float*)d_out;
    float* e_sq = (float*)d_ws;                    // 512 floats of scratch

    hipLaunchKernelGGL(vq_prep, dim3(2), dim3(256), 0, stream, emb, e_sq);
    const int nblocks = (32 * 64 * 64) / BPIX;     // 1024
    hipLaunchKernelGGL(vq_main, dim3(nblocks), dim3(512), 0, stream,
                       x, emb, e_sq, out);
}